// Round 11
// baseline (117.471 us; speedup 1.0000x reference)
//
#include <hip/hip_runtime.h>
#include <hip/hip_fp16.h>

#define F0 21
#define F1 128
#define F2 64
#define NPB 49            // nodes per bucket (local id fits 7 bits)
#define MAXB 1024         // max buckets; NB = ceil(n/NPB) <= MAXB
#define CAP 1536          // ebuf slots per bucket (Poisson mean 784; 27-sigma headroom)
#define IDM 0x1FFFFu      // 17-bit node id mask (n < 131072)
#define BIN_TPB 1024
#define BIN_EPT 8
#define BIN_EPB (BIN_TPB * BIN_EPT)   // 8192 edges/block; rank <= 8191 -> 13 bits
#define OFFS 64           // offG row stride (>= NPB+1)
#define AGG_TPB 384       // 6 threads/node in gather phase (3 cols x 2 halves)
#define PSTR 26           // pstage row stride (floats)

// per-branch bundle
struct GP {
    const float* x;       // [n, F0]
    const int*   src;     // [E]
    const int*   dst;     // [E]
    int*      bcntD;      // [MAXB] dst-system fill counts (memset 0)
    int*      bcntS;      // [MAXB] src-system fill counts (memset 0)
    unsigned* ebufD;      // [MAXB*CAP] packed (t_local<<17)|src_id
    unsigned* ebufS;      // [MAXB*CAP] packed (s_local<<17)|dst_id
    int*      offG;       // [MAXB*OFFS] per-bucket node prefix (dst system)
    float*    dinv;       // [n]
    __half*   y;          // [n*24] fp16 dinv[s]*x[s][k], padded to 24
    float*    part;       // [NB*F1]
    float*    outp;       // [F2]
};

// ---- binning: one (branch, system) per block-z; key system D: by dst, S: by src ----
__global__ void __launch_bounds__(BIN_TPB) k_binD(GP g0, GP g1, int E) {
    GP g = blockIdx.y ? g1 : g0;
    int sys = blockIdx.z;
    const int* key = sys ? g.src : g.dst;
    const int* pay = sys ? g.dst : g.src;
    int*       bcnt = sys ? g.bcntS : g.bcntD;
    unsigned*  ebuf = sys ? g.ebufS : g.ebufD;

    __shared__ int h[MAXB];
    __shared__ int base[MAXB];
    int tid = threadIdx.x;
    h[tid] = 0;
    __syncthreads();
    int e0 = blockIdx.x * BIN_EPB;
    unsigned pk[BIN_EPT], br[BIN_EPT];
    #pragma unroll
    for (int i = 0; i < BIN_EPT; ++i) {
        int e = e0 + i * BIN_TPB + tid;
        if (e < E) {
            int k = key[e], p = pay[e];
            unsigned bk = (unsigned)k / NPB;
            int r = atomicAdd(&h[bk], 1);
            pk[i] = ((unsigned)(k - (int)bk * NPB) << 17) | (unsigned)p;
            br[i] = (bk << 13) | (unsigned)r;
        }
    }
    __syncthreads();
    int c0 = h[tid];
    if (c0) base[tid] = atomicAdd(&bcnt[tid], c0);
    __syncthreads();
    #pragma unroll
    for (int i = 0; i < BIN_EPT; ++i) {
        int e = e0 + i * BIN_TPB + tid;
        if (e < E) {
            unsigned bk = br[i] >> 13;
            unsigned p = (unsigned)base[bk] + (br[i] & 8191u);
            if (p < CAP) ebuf[(size_t)bk * CAP + p] = pk[i];   // overflow: drop (P~1e-30)
        }
    }
}

// ---- fused per-bucket: degree count -> dinv, node prefix offG (wave scan), y rows ----
__global__ void __launch_bounds__(256) k_dprep(GP g0, GP g1, int n) {
    GP g = blockIdx.y ? g1 : g0;
    __shared__ int cnt[NPB];
    __shared__ float dls[NPB];
    int tid = threadIdx.x;
    int slot = blockIdx.x;
    int node0 = slot * NPB;
    int nn = min(NPB, n - node0);
    if (tid < NPB) cnt[tid] = 0;
    __syncthreads();
    int s0 = slot * CAP;
    int s1 = s0 + min(g.bcntD[slot], CAP);
    for (int e = s0 + tid; e < s1; e += 256) atomicAdd(&cnt[g.ebufD[e] >> 17], 1);
    __syncthreads();
    if (tid < 64) {                       // wave-parallel exclusive scan of cnt[0..NPB)
        int c = (tid < NPB) ? cnt[tid] : 0;
        int v = c;
        #pragma unroll
        for (int d = 1; d < 64; d <<= 1) {
            int t = __shfl_up(v, d, 64);
            if (tid >= d) v += t;
        }
        if (tid < NPB) g.offG[slot * OFFS + tid] = v - c;     // exclusive
        if (tid == NPB - 1) g.offG[slot * OFFS + NPB] = v;    // total
    }
    if (tid < NPB) {
        float di = rsqrtf(1.0f + (float)cnt[tid]);
        dls[tid] = di;
        if (tid < nn) g.dinv[node0 + tid] = di;
    }
    __syncthreads();
    // vectorized y-write: one __half2 (u32) per thread-iteration
    unsigned* y32 = (unsigned*)g.y;
    int tot = nn * 12;
    for (int i = tid; i < tot; i += 256) {
        int tl = i / 12, m = i - tl * 12;
        int node = node0 + tl;
        int k0 = 2 * m;
        float f0 = (k0 < F0)     ? dls[tl] * g.x[(size_t)node * F0 + k0]     : 0.0f;
        float f1 = (k0 + 1 < F0) ? dls[tl] * g.x[(size_t)node * F0 + k0 + 1] : 0.0f;
        __half2 h = __floats2half2_rn(f0, f1);
        y32[(size_t)node * 12 + m] = *(unsigned*)&h;
    }
}

// ---- main: LDS counting-sort + wl accumulate -> split register agg -> half2 W1 reduce ----
// 1-D grid: blocks with (bid&7)<4 run branch 0, others branch 1 (XCD L2 split).
__global__ void __launch_bounds__(AGG_TPB) k_agg(GP g0, GP g1,
        const float* __restrict__ W1, const float* __restrict__ b1v, int n, int NB) {
    unsigned bid = blockIdx.x;
    unsigned qq = bid >> 3, rr = bid & 7;
    int branch = (rr >= 4);
    int slot = (int)(qq * 4 + (rr & 3));
    if (slot >= NB) return;                       // uniform per block
    GP g = branch ? g1 : g0;

    __shared__ unsigned aggh[NPB * 12];           // half2-packed agg rows (2352 B)
    __shared__ int   eloc[CAP];                   // 6144 B
    __shared__ int   off[NPB + 1];
    __shared__ int   cur[NPB];
    __shared__ float wl[NPB];                     // wout for this node range
    __shared__ float red[AGG_TPB];
    __shared__ float pstage[NPB * PSTR];          // fp32 half-0 partials (5096 B)

    int tid = threadIdx.x;
    int j = tid & (F1 - 1), hf = tid >> 7;        // hf in {0,1,2}
    int s0 = slot * CAP;
    int s1 = s0 + min(g.bcntD[slot], CAP);
    int node0 = slot * NPB;
    int nn = min(NPB, n - node0);

    // W1 column -> half2 registers
    __half2 wh[12];
    {
        float w[F0];
        #pragma unroll
        for (int k = 0; k < F0; ++k) w[k] = W1[k * F1 + j];
        #pragma unroll
        for (int m = 0; m < 10; ++m) wh[m] = __floats2half2_rn(w[2 * m], w[2 * m + 1]);
        wh[10] = __floats2half2_rn(w[20], 0.0f);
        wh[11] = __floats2half2_rn(0.0f, 0.0f);
    }
    float bj = b1v[j];

    if (tid <= NPB) off[tid] = g.offG[slot * OFFS + tid];
    if (tid < NPB) wl[tid] = 0.0f;
    __syncthreads();
    if (tid < NPB) cur[tid] = off[tid];
    __syncthreads();
    // dst-sorted edges -> eloc (1 LDS atomic/edge)
    for (int e = s0 + tid; e < s1; e += AGG_TPB) {
        unsigned u = g.ebufD[e];
        int p = atomicAdd(&cur[u >> 17], 1);
        eloc[p] = (int)(u & IDM);
    }
    // src-sorted edges -> wl[s_local] += dinv[dst]  (L2-hot gather, LDS atomic)
    {
        int t0 = slot * CAP;
        int t1 = t0 + min(g.bcntS[slot], CAP);
        for (int e = t0 + tid; e < t1; e += AGG_TPB) {
            unsigned u = g.ebufS[e];
            atomicAdd(&wl[u >> 17], g.dinv[u & IDM]);
        }
    }
    __syncthreads();

    // gather phase: 6 threads/node = 3 column-chunks x 2 edge-halves
    const uint4* yb = (const uint4*)g.y;
    float a[8] = {0, 0, 0, 0, 0, 0, 0, 0};
    int tl = -1, kc = 0, half = 0;
    if (tid < 6 * NPB) {
        int t6 = tid / 6, sub = tid - t6 * 6;
        if (t6 < nn) {
            tl = t6; kc = sub % 3; half = sub / 3;
            int node = node0 + tl;
            int eA = off[tl], eB = off[tl + 1];
            int mid = (eA + eB + 1) >> 1;
            int lo = half ? mid : eA;
            int hi = half ? eB  : mid;
            int e = lo;
            for (; e + 1 < hi; e += 2) {           // 2 independent gathers/iter
                int sA = eloc[e], sB = eloc[e + 1];
                uint4 vA = yb[(size_t)sA * 3 + kc];
                uint4 vB = yb[(size_t)sB * 3 + kc];
                const unsigned* wA = (const unsigned*)&vA;
                const unsigned* wB = (const unsigned*)&vB;
                #pragma unroll
                for (int m = 0; m < 4; ++m) {
                    float2 fA = __half22float2(*(const __half2*)&wA[m]);
                    float2 fB = __half22float2(*(const __half2*)&wB[m]);
                    a[2 * m]     += fA.x + fB.x;
                    a[2 * m + 1] += fA.y + fB.y;
                }
            }
            // tail edge + (half1 only) self row
            for (int q = 0; q < 2; ++q) {
                int s = (q == 0) ? ((e < hi) ? eloc[e] : -1) : (half ? node : -1);
                if (s >= 0) {
                    uint4 v = yb[(size_t)s * 3 + kc];
                    const unsigned* vw = (const unsigned*)&v;
                    #pragma unroll
                    for (int m = 0; m < 4; ++m) {
                        float2 f = __half22float2(*(const __half2*)&vw[m]);
                        a[2 * m]     += f.x;
                        a[2 * m + 1] += f.y;
                    }
                }
            }
            if (half == 0) {
                #pragma unroll
                for (int m = 0; m < 8; ++m) pstage[tl * PSTR + kc * 8 + m] = a[m];
            }
        }
    }
    __syncthreads();
    if (tl >= 0 && half == 1) {                    // combine fp32, pack half2
        #pragma unroll
        for (int m = 0; m < 8; ++m) a[m] += pstage[tl * PSTR + kc * 8 + m];
        __half2 h0 = __floats2half2_rn(a[0], a[1]);
        __half2 h1 = __floats2half2_rn(a[2], a[3]);
        __half2 h2 = __floats2half2_rn(a[4], a[5]);
        __half2 h3 = __floats2half2_rn(a[6], a[7]);
        uint4 o;
        o.x = *(unsigned*)&h0; o.y = *(unsigned*)&h1;
        o.z = *(unsigned*)&h2; o.w = *(unsigned*)&h3;
        *(uint4*)&aggh[tl * 12 + kc * 4] = o;      // 48B rows, 16B-aligned
    }
    __syncthreads();

    // v_j = b1[j] + di * (agg[tl] . W1[:,j]); acc += c * relu(v); 3 node-slices
    float acc = 0.0f;
    for (int t2 = hf; t2 < nn; t2 += 3) {
        int node = node0 + t2;
        float di = g.dinv[node];                         // broadcast
        float co = di * wl[t2] + di * di;
        const uint4* ar = (const uint4*)&aggh[t2 * 12];  // 3 x ds_read_b128 broadcast
        __half2 hac = __floats2half2_rn(0.0f, 0.0f);
        #pragma unroll
        for (int m = 0; m < 3; ++m) {
            uint4 v = ar[m];
            const unsigned* vw = (const unsigned*)&v;
            #pragma unroll
            for (int q = 0; q < 4; ++q)
                hac = __hfma2(*(const __half2*)&vw[q], wh[m * 4 + q], hac);
        }
        float dot = __low2float(hac) + __high2float(hac);
        acc += co * fmaxf(bj + di * dot, 0.0f);
    }
    red[tid] = acc;
    __syncthreads();
    if (hf == 0) g.part[(size_t)slot * F1 + j] = red[j] + red[j + F1] + red[j + 2 * F1];
}

// ---- reduce part over buckets, then out = b2 + invN * (sacc @ W2) ----
__global__ void __launch_bounds__(1024) k_fin(GP g0, GP g1,
        const float* __restrict__ W2, const float* __restrict__ b2,
        float invN, int NB) {
    GP g = blockIdx.y ? g1 : g0;
    __shared__ float red[1024];
    __shared__ float sv[F1];
    int tid = threadIdx.x;
    int j = tid & (F1 - 1), h = tid >> 7;   // 8 slices
    float a = 0.0f;
    for (int r = h; r < NB; r += 8) a += g.part[(size_t)r * F1 + j];
    red[tid] = a;
    __syncthreads();
    for (int s = 4; s >= 1; s >>= 1) {
        if (h < s) red[tid] += red[tid + s * F1];
        __syncthreads();
    }
    if (tid < F1) sv[tid] = red[tid];
    __syncthreads();
    if (tid < F2) {
        float o = 0.0f;
        #pragma unroll 8
        for (int k = 0; k < F1; ++k) o += sv[k] * W2[k * F2 + tid];
        g.outp[tid] = b2[tid] + invN * o;
    }
}

// ---------------- fallback (round-1 algorithm, ~4.7 MB ws) ----------------
__global__ void o_deg(const int* __restrict__ dst, float* __restrict__ deg, int E) {
    int i = blockIdx.x * blockDim.x + threadIdx.x;
    int stride = gridDim.x * blockDim.x;
    for (; i < E; i += stride) atomicAdd(&deg[dst[i]], 1.0f);
}
__global__ void o_dinv(const float* __restrict__ deg, float* __restrict__ dinv, int n) {
    int i = blockIdx.x * blockDim.x + threadIdx.x;
    if (i < n) dinv[i] = rsqrtf(deg[i] + 1.0f);
}
__global__ void o_edge(const int* __restrict__ src, const int* __restrict__ dst,
                       const float* __restrict__ x, const float* __restrict__ dinv,
                       float* __restrict__ wout, float* __restrict__ aggx, int E) {
    int total = E * F0;
    int i = blockIdx.x * blockDim.x + threadIdx.x;
    int stride = gridDim.x * blockDim.x;
    for (; i < total; i += stride) {
        int e = i / F0;
        int k = i - e * F0;
        int s = src[e], t = dst[e];
        float ds = dinv[s], dt = dinv[t];
        if (k == 0) atomicAdd(&wout[s], dt);
        atomicAdd(&aggx[t * F0 + k], x[s * F0 + k] * (ds * dt));
    }
}
__global__ void __launch_bounds__(F1) o_node(
        const float* __restrict__ x, const float* __restrict__ aggx,
        const float* __restrict__ dinv, const float* __restrict__ wout,
        const float* __restrict__ W1, const float* __restrict__ b1,
        float* __restrict__ sacc, int n) {
    __shared__ float w1s[F0 * F1];
    __shared__ float b1s[F1];
    int j = threadIdx.x;
    for (int idx = j; idx < F0 * F1; idx += F1) w1s[idx] = W1[idx];
    b1s[j] = b1[j];
    __syncthreads();
    float acc = 0.0f;
    for (int node = blockIdx.x; node < n; node += gridDim.x) {
        float di = dinv[node];
        float di2 = di * di;
        float c = di * wout[node] + di2;
        const float* xr = x + (size_t)node * F0;
        const float* ar = aggx + (size_t)node * F0;
        float v = b1s[j];
        #pragma unroll
        for (int k = 0; k < F0; ++k) v += (ar[k] + xr[k] * di2) * w1s[k * F1 + j];
        acc += c * fmaxf(v, 0.0f);
    }
    atomicAdd(&sacc[j], acc);
}
__global__ void o_final(const float* __restrict__ sacc, const float* __restrict__ W2,
                        const float* __restrict__ b2, float* __restrict__ out, float invN) {
    int j = threadIdx.x;
    float acc = 0.0f;
    #pragma unroll 8
    for (int k = 0; k < F1; ++k) acc += sacc[k] * W2[k * F2 + j];
    out[j] = b2[j] + invN * acc;
}

extern "C" void kernel_launch(void* const* d_in, const int* in_sizes, int n_in,
                              void* d_out, int out_size, void* d_ws, size_t ws_size,
                              hipStream_t stream) {
    const float* W1 = (const float*)d_in[4];
    const float* b1 = (const float*)d_in[5];
    const float* W2 = (const float*)d_in[6];
    const float* b2 = (const float*)d_in[7];
    float* out = (float*)d_out;

    const int n = in_sizes[0] / F0;   // 50000
    const int E = in_sizes[2] / 2;    // 800000
    const int NB = (n + NPB - 1) / NPB;
    const float invN = 1.0f / (float)n;

    // ---- workspace layout ----
    size_t off = 0;
    auto alloc = [&](size_t bytes) { size_t r = off; off += (bytes + 255) & ~(size_t)255; return r; };
    size_t z_bcnt  = alloc(4 * (size_t)MAXB * 4);   // [b0:D][b0:S][b1:D][b1:S], memset 0
    size_t z_ebufD = alloc(2 * (size_t)MAXB * CAP * 4);
    size_t z_ebufS = alloc(2 * (size_t)MAXB * CAP * 4);
    size_t z_offG  = alloc(2 * (size_t)MAXB * OFFS * 4);
    size_t z_dinv  = alloc(2 * (size_t)n * 4);
    size_t z_y     = alloc(2 * (size_t)n * 24 * 2);
    size_t z_part  = alloc(2 * (size_t)NB * F1 * 4);
    size_t need = off;

    char* ws = (char*)d_ws;
    bool ok = (NB <= MAXB) && (n < 131072) && (E > 0) && (ws_size >= need);

    if (ok) {
        auto mkg = [&](int b) {
            GP g;
            g.x     = (const float*)d_in[b];
            const int* e = (const int*)d_in[2 + b];
            g.src   = e;
            g.dst   = e + E;
            g.bcntD = (int*)(ws + z_bcnt) + (size_t)(2 * b + 0) * MAXB;
            g.bcntS = (int*)(ws + z_bcnt) + (size_t)(2 * b + 1) * MAXB;
            g.ebufD = (unsigned*)(ws + z_ebufD) + (size_t)b * MAXB * CAP;
            g.ebufS = (unsigned*)(ws + z_ebufS) + (size_t)b * MAXB * CAP;
            g.offG  = (int*)(ws + z_offG) + (size_t)b * MAXB * OFFS;
            g.dinv  = (float*)(ws + z_dinv) + (size_t)b * n;
            g.y     = (__half*)(ws + z_y) + (size_t)b * n * 24;
            g.part  = (float*)(ws + z_part) + (size_t)b * NB * F1;
            g.outp  = out + b * F2;
            return g;
        };
        GP g0 = mkg(0), g1 = mkg(1);

        int binBlocks = (E + BIN_EPB - 1) / BIN_EPB;
        int NB4 = (NB + 3) / 4;
        (void)hipMemsetAsync(ws + z_bcnt, 0, 4 * (size_t)MAXB * 4, stream);
        k_binD <<<dim3(binBlocks, 2, 2), BIN_TPB, 0, stream>>>(g0, g1, E);
        k_dprep<<<dim3(NB, 2), 256, 0, stream>>>(g0, g1, n);
        k_agg  <<<dim3(8 * NB4), AGG_TPB, 0, stream>>>(g0, g1, W1, b1, n, NB);
        k_fin  <<<dim3(1, 2), 1024, 0, stream>>>(g0, g1, W2, b2, invN, NB);
    } else {
        // fallback: round-1 algorithm (atomic scatter), ~4.7 MB
        float* wsf   = (float*)d_ws;
        float* fdeg  = wsf;
        float* fwout = wsf + (size_t)n;
        float* faggx = wsf + 2 * (size_t)n;
        float* fsacc = wsf + 2 * (size_t)n + (size_t)F0 * n;
        float* fdinv = fsacc + F1;
        size_t zero_bytes = ((size_t)23 * n + F1) * sizeof(float);
        for (int b = 0; b < 2; ++b) {
            (void)hipMemsetAsync(wsf, 0, zero_bytes, stream);
            const int* srcp = (const int*)d_in[2 + b];
            const int* dstp = srcp + E;
            const float* x = (const float*)d_in[b];
            o_deg <<<1024, 256, 0, stream>>>(dstp, fdeg, E);
            o_dinv<<<(n + 255) / 256, 256, 0, stream>>>(fdeg, fdinv, n);
            o_edge<<<2048, 256, 0, stream>>>(srcp, dstp, x, fdinv, fwout, faggx, E);
            o_node<<<512, F1, 0, stream>>>(x, faggx, fdinv, fwout, W1, b1, fsacc, n);
            o_final<<<1, F2, 0, stream>>>(fsacc, W2, b2, out + b * F2, invN);
        }
    }
}

// Round 12
// 114.132 us; speedup vs baseline: 1.0293x; 1.0293x over previous
//
#include <hip/hip_runtime.h>
#include <hip/hip_fp16.h>

#define F0 21
#define F1 128
#define F2 64
#define NPB 49            // nodes per bucket (local id fits 7 bits)
#define MAXB 1024         // max buckets; NB = ceil(n/NPB) <= MAXB
#define CAP 1536          // ebuf slots per bucket (Poisson mean 784; 27-sigma headroom)
#define IDM 0x1FFFFu      // 17-bit node id mask (n < 131072)
#define BIN_TPB 1024
#define BIN_EPT 8
#define BIN_EPB (BIN_TPB * BIN_EPT)   // 8192 edges/block; rank <= 8191 -> 13 bits
#define OFFS 64           // offG row stride (>= NPB+1)

// per-branch bundle
struct GP {
    const float* x;       // [n, F0]
    const int*   src;     // [E]
    const int*   dst;     // [E]
    int*      bcntD;      // [MAXB] dst-system fill counts (memset 0)
    int*      bcntS;      // [MAXB] src-system fill counts (memset 0)
    unsigned* ebufD;      // [MAXB*CAP] packed (t_local<<17)|src_id
    unsigned* ebufS;      // [MAXB*CAP] packed (s_local<<17)|dst_id
    int*      offG;       // [MAXB*OFFS] per-bucket node prefix (dst system)
    float*    dinv;       // [n]
    __half*   y;          // [n*24] fp16 dinv[s]*x[s][k], padded to 24
    float*    part;       // [NB*F1]
    float*    outp;       // [F2]
};

// ---- binning: one (branch, system) per block-z; key system D: by dst, S: by src ----
__global__ void __launch_bounds__(BIN_TPB) k_binD(GP g0, GP g1, int E) {
    GP g = blockIdx.y ? g1 : g0;
    int sys = blockIdx.z;
    const int* key = sys ? g.src : g.dst;
    const int* pay = sys ? g.dst : g.src;
    int*       bcnt = sys ? g.bcntS : g.bcntD;
    unsigned*  ebuf = sys ? g.ebufS : g.ebufD;

    __shared__ int h[MAXB];
    __shared__ int base[MAXB];
    int tid = threadIdx.x;
    h[tid] = 0;
    __syncthreads();
    int e0 = blockIdx.x * BIN_EPB;
    unsigned pk[BIN_EPT], br[BIN_EPT];
    #pragma unroll
    for (int i = 0; i < BIN_EPT; ++i) {
        int e = e0 + i * BIN_TPB + tid;
        if (e < E) {
            int k = key[e], p = pay[e];
            unsigned bk = (unsigned)k / NPB;
            int r = atomicAdd(&h[bk], 1);
            pk[i] = ((unsigned)(k - (int)bk * NPB) << 17) | (unsigned)p;
            br[i] = (bk << 13) | (unsigned)r;
        }
    }
    __syncthreads();
    int c0 = h[tid];
    if (c0) base[tid] = atomicAdd(&bcnt[tid], c0);
    __syncthreads();
    #pragma unroll
    for (int i = 0; i < BIN_EPT; ++i) {
        int e = e0 + i * BIN_TPB + tid;
        if (e < E) {
            unsigned bk = br[i] >> 13;
            unsigned p = (unsigned)base[bk] + (br[i] & 8191u);
            if (p < CAP) ebuf[(size_t)bk * CAP + p] = pk[i];   // overflow: drop (P~1e-30)
        }
    }
}

// ---- fused per-bucket: degree count -> dinv, node prefix offG (wave scan), y rows ----
__global__ void __launch_bounds__(256) k_dprep(GP g0, GP g1, int n) {
    GP g = blockIdx.y ? g1 : g0;
    __shared__ int cnt[NPB];
    __shared__ float dls[NPB];
    int tid = threadIdx.x;
    int slot = blockIdx.x;
    int node0 = slot * NPB;
    int nn = min(NPB, n - node0);
    if (tid < NPB) cnt[tid] = 0;
    __syncthreads();
    int s0 = slot * CAP;
    int s1 = s0 + min(g.bcntD[slot], CAP);
    for (int e = s0 + tid; e < s1; e += 256) atomicAdd(&cnt[g.ebufD[e] >> 17], 1);
    __syncthreads();
    if (tid < 64) {                       // wave-parallel exclusive scan of cnt[0..NPB)
        int c = (tid < NPB) ? cnt[tid] : 0;
        int v = c;
        #pragma unroll
        for (int d = 1; d < 64; d <<= 1) {
            int t = __shfl_up(v, d, 64);
            if (tid >= d) v += t;
        }
        if (tid < NPB) g.offG[slot * OFFS + tid] = v - c;     // exclusive
        if (tid == NPB - 1) g.offG[slot * OFFS + NPB] = v;    // total
    }
    if (tid < NPB) {
        float di = rsqrtf(1.0f + (float)cnt[tid]);
        dls[tid] = di;
        if (tid < nn) g.dinv[node0 + tid] = di;
    }
    __syncthreads();
    int tot = nn * 24;
    for (int i = tid; i < tot; i += 256) {
        int tl = i / 24, k = i - tl * 24;
        float v = (k < F0) ? dls[tl] * g.x[(size_t)(node0 + tl) * F0 + k] : 0.0f;
        g.y[(size_t)(node0 + tl) * 24 + k] = __float2half(v);
    }
}

// ---- main: LDS counting-sort + wl accumulate -> register agg -> half2 W1 reduce ----
// 1-D grid: blocks with (bid&7)<4 run branch 0, others branch 1 (XCD L2 split).
__global__ void __launch_bounds__(256) k_agg(GP g0, GP g1,
        const float* __restrict__ W1, const float* __restrict__ b1v, int n, int NB) {
    unsigned bid = blockIdx.x;
    unsigned qq = bid >> 3, rr = bid & 7;
    int branch = (rr >= 4);
    int slot = (int)(qq * 4 + (rr & 3));
    if (slot >= NB) return;                       // uniform per block
    GP g = branch ? g1 : g0;

    __shared__ unsigned aggh[NPB * 12];           // half2-packed agg rows (2352 B)
    __shared__ int   eloc[CAP];                   // 6144 B
    __shared__ int   off[NPB + 1];
    __shared__ int   cur[NPB];
    __shared__ float wl[NPB];                     // wout for this node range
    __shared__ float red[256];

    int tid = threadIdx.x;
    int j = tid & (F1 - 1), hf = tid >> 7;
    int s0 = slot * CAP;
    int s1 = s0 + min(g.bcntD[slot], CAP);
    int node0 = slot * NPB;
    int nn = min(NPB, n - node0);

    // W1 column -> half2 registers
    __half2 wh[12];
    {
        float w[F0];
        #pragma unroll
        for (int k = 0; k < F0; ++k) w[k] = W1[k * F1 + j];
        #pragma unroll
        for (int m = 0; m < 10; ++m) wh[m] = __floats2half2_rn(w[2 * m], w[2 * m + 1]);
        wh[10] = __floats2half2_rn(w[20], 0.0f);
        wh[11] = __floats2half2_rn(0.0f, 0.0f);
    }
    float bj = b1v[j];

    if (tid <= NPB) off[tid] = g.offG[slot * OFFS + tid];
    if (tid < NPB) wl[tid] = 0.0f;
    __syncthreads();
    if (tid < NPB) cur[tid] = off[tid];
    __syncthreads();
    // dst-sorted edges -> eloc (1 LDS atomic/edge)
    for (int e = s0 + tid; e < s1; e += 256) {
        unsigned u = g.ebufD[e];
        int p = atomicAdd(&cur[u >> 17], 1);
        eloc[p] = (int)(u & IDM);
    }
    // src-sorted edges -> wl[s_local] += dinv[dst]  (L2-hot gather, LDS atomic)
    {
        int t0 = slot * CAP;
        int t1 = t0 + min(g.bcntS[slot], CAP);
        for (int e = t0 + tid; e < t1; e += 256) {
            unsigned u = g.ebufS[e];
            atomicAdd(&wl[u >> 17], g.dinv[u & IDM]);
        }
    }
    __syncthreads();

    const uint4* yb = (const uint4*)g.y;
    if (tid < 3 * NPB) {
        int tl = tid / 3, kc = tid - (tid / 3) * 3;
        if (tl < nn) {
            int node = node0 + tl;
            float a[8] = {0, 0, 0, 0, 0, 0, 0, 0};
            int eA = off[tl], eB = off[tl + 1];
            int e = eA;
            // 2-way unrolled: issue two independent uint4 gathers per iteration
            for (; e + 1 < eB; e += 2) {
                int sA = eloc[e], sB = eloc[e + 1];
                uint4 vA = yb[(size_t)sA * 3 + kc];
                uint4 vB = yb[(size_t)sB * 3 + kc];
                const unsigned* wA = (const unsigned*)&vA;
                const unsigned* wB = (const unsigned*)&vB;
                #pragma unroll
                for (int m = 0; m < 4; ++m) {
                    float2 fA = __half22float2(*(const __half2*)&wA[m]);
                    float2 fB = __half22float2(*(const __half2*)&wB[m]);
                    a[2 * m]     += fA.x + fB.x;
                    a[2 * m + 1] += fA.y + fB.y;
                }
            }
            // tail edge (if odd count) + self row
            for (int q = 0; q < 2; ++q) {
                int s = (q == 0) ? ((e < eB) ? eloc[e] : -1) : node;
                if (s >= 0) {
                    uint4 v = yb[(size_t)s * 3 + kc];
                    const unsigned* vw = (const unsigned*)&v;
                    #pragma unroll
                    for (int m = 0; m < 4; ++m) {
                        float2 f = __half22float2(*(const __half2*)&vw[m]);
                        a[2 * m]     += f.x;
                        a[2 * m + 1] += f.y;
                    }
                }
            }
            __half2 h0 = __floats2half2_rn(a[0], a[1]);
            __half2 h1 = __floats2half2_rn(a[2], a[3]);
            __half2 h2 = __floats2half2_rn(a[4], a[5]);
            __half2 h3 = __floats2half2_rn(a[6], a[7]);
            uint4 o;
            o.x = *(unsigned*)&h0; o.y = *(unsigned*)&h1;
            o.z = *(unsigned*)&h2; o.w = *(unsigned*)&h3;
            *(uint4*)&aggh[tl * 12 + kc * 4] = o;        // 48B rows, 16B-aligned
        }
    }
    __syncthreads();

    // v_j = b1[j] + di * (agg[tl] . W1[:,j]); acc += c * relu(v)
    float acc = 0.0f;
    for (int tl = hf; tl < nn; tl += 2) {
        int node = node0 + tl;
        float di = g.dinv[node];                         // broadcast
        float co = di * wl[tl] + di * di;
        const uint4* ar = (const uint4*)&aggh[tl * 12];  // 3 x ds_read_b128 broadcast
        __half2 hac = __floats2half2_rn(0.0f, 0.0f);
        #pragma unroll
        for (int m = 0; m < 3; ++m) {
            uint4 v = ar[m];
            const unsigned* vw = (const unsigned*)&v;
            #pragma unroll
            for (int q = 0; q < 4; ++q)
                hac = __hfma2(*(const __half2*)&vw[q], wh[m * 4 + q], hac);
        }
        float dot = __low2float(hac) + __high2float(hac);
        acc += co * fmaxf(bj + di * dot, 0.0f);
    }
    red[tid] = acc;
    __syncthreads();
    if (hf == 0) g.part[(size_t)slot * F1 + j] = red[j] + red[j + F1];
}

// ---- reduce part over buckets, then out = b2 + invN * (sacc @ W2) ----
__global__ void __launch_bounds__(1024) k_fin(GP g0, GP g1,
        const float* __restrict__ W2, const float* __restrict__ b2,
        float invN, int NB) {
    GP g = blockIdx.y ? g1 : g0;
    __shared__ float red[1024];
    __shared__ float sv[F1];
    int tid = threadIdx.x;
    int j = tid & (F1 - 1), h = tid >> 7;   // 8 slices
    float a = 0.0f;
    for (int r = h; r < NB; r += 8) a += g.part[(size_t)r * F1 + j];
    red[tid] = a;
    __syncthreads();
    for (int s = 4; s >= 1; s >>= 1) {
        if (h < s) red[tid] += red[tid + s * F1];
        __syncthreads();
    }
    if (tid < F1) sv[tid] = red[tid];
    __syncthreads();
    if (tid < F2) {
        float o = 0.0f;
        #pragma unroll 8
        for (int k = 0; k < F1; ++k) o += sv[k] * W2[k * F2 + tid];
        g.outp[tid] = b2[tid] + invN * o;
    }
}

// ---------------- fallback (round-1 algorithm, ~4.7 MB ws) ----------------
__global__ void o_deg(const int* __restrict__ dst, float* __restrict__ deg, int E) {
    int i = blockIdx.x * blockDim.x + threadIdx.x;
    int stride = gridDim.x * blockDim.x;
    for (; i < E; i += stride) atomicAdd(&deg[dst[i]], 1.0f);
}
__global__ void o_dinv(const float* __restrict__ deg, float* __restrict__ dinv, int n) {
    int i = blockIdx.x * blockDim.x + threadIdx.x;
    if (i < n) dinv[i] = rsqrtf(deg[i] + 1.0f);
}
__global__ void o_edge(const int* __restrict__ src, const int* __restrict__ dst,
                       const float* __restrict__ x, const float* __restrict__ dinv,
                       float* __restrict__ wout, float* __restrict__ aggx, int E) {
    int total = E * F0;
    int i = blockIdx.x * blockDim.x + threadIdx.x;
    int stride = gridDim.x * blockDim.x;
    for (; i < total; i += stride) {
        int e = i / F0;
        int k = i - e * F0;
        int s = src[e], t = dst[e];
        float ds = dinv[s], dt = dinv[t];
        if (k == 0) atomicAdd(&wout[s], dt);
        atomicAdd(&aggx[t * F0 + k], x[s * F0 + k] * (ds * dt));
    }
}
__global__ void __launch_bounds__(F1) o_node(
        const float* __restrict__ x, const float* __restrict__ aggx,
        const float* __restrict__ dinv, const float* __restrict__ wout,
        const float* __restrict__ W1, const float* __restrict__ b1,
        float* __restrict__ sacc, int n) {
    __shared__ float w1s[F0 * F1];
    __shared__ float b1s[F1];
    int j = threadIdx.x;
    for (int idx = j; idx < F0 * F1; idx += F1) w1s[idx] = W1[idx];
    b1s[j] = b1[j];
    __syncthreads();
    float acc = 0.0f;
    for (int node = blockIdx.x; node < n; node += gridDim.x) {
        float di = dinv[node];
        float di2 = di * di;
        float c = di * wout[node] + di2;
        const float* xr = x + (size_t)node * F0;
        const float* ar = aggx + (size_t)node * F0;
        float v = b1s[j];
        #pragma unroll
        for (int k = 0; k < F0; ++k) v += (ar[k] + xr[k] * di2) * w1s[k * F1 + j];
        acc += c * fmaxf(v, 0.0f);
    }
    atomicAdd(&sacc[j], acc);
}
__global__ void o_final(const float* __restrict__ sacc, const float* __restrict__ W2,
                        const float* __restrict__ b2, float* __restrict__ out, float invN) {
    int j = threadIdx.x;
    float acc = 0.0f;
    #pragma unroll 8
    for (int k = 0; k < F1; ++k) acc += sacc[k] * W2[k * F2 + j];
    out[j] = b2[j] + invN * acc;
}

extern "C" void kernel_launch(void* const* d_in, const int* in_sizes, int n_in,
                              void* d_out, int out_size, void* d_ws, size_t ws_size,
                              hipStream_t stream) {
    const float* W1 = (const float*)d_in[4];
    const float* b1 = (const float*)d_in[5];
    const float* W2 = (const float*)d_in[6];
    const float* b2 = (const float*)d_in[7];
    float* out = (float*)d_out;

    const int n = in_sizes[0] / F0;   // 50000
    const int E = in_sizes[2] / 2;    // 800000
    const int NB = (n + NPB - 1) / NPB;
    const float invN = 1.0f / (float)n;

    // ---- workspace layout ----
    size_t off = 0;
    auto alloc = [&](size_t bytes) { size_t r = off; off += (bytes + 255) & ~(size_t)255; return r; };
    size_t z_bcnt  = alloc(4 * (size_t)MAXB * 4);   // [b0:D][b0:S][b1:D][b1:S], memset 0
    size_t z_ebufD = alloc(2 * (size_t)MAXB * CAP * 4);
    size_t z_ebufS = alloc(2 * (size_t)MAXB * CAP * 4);
    size_t z_offG  = alloc(2 * (size_t)MAXB * OFFS * 4);
    size_t z_dinv  = alloc(2 * (size_t)n * 4);
    size_t z_y     = alloc(2 * (size_t)n * 24 * 2);
    size_t z_part  = alloc(2 * (size_t)NB * F1 * 4);
    size_t need = off;

    char* ws = (char*)d_ws;
    bool ok = (NB <= MAXB) && (n < 131072) && (E > 0) && (ws_size >= need);

    if (ok) {
        auto mkg = [&](int b) {
            GP g;
            g.x     = (const float*)d_in[b];
            const int* e = (const int*)d_in[2 + b];
            g.src   = e;
            g.dst   = e + E;
            g.bcntD = (int*)(ws + z_bcnt) + (size_t)(2 * b + 0) * MAXB;
            g.bcntS = (int*)(ws + z_bcnt) + (size_t)(2 * b + 1) * MAXB;
            g.ebufD = (unsigned*)(ws + z_ebufD) + (size_t)b * MAXB * CAP;
            g.ebufS = (unsigned*)(ws + z_ebufS) + (size_t)b * MAXB * CAP;
            g.offG  = (int*)(ws + z_offG) + (size_t)b * MAXB * OFFS;
            g.dinv  = (float*)(ws + z_dinv) + (size_t)b * n;
            g.y     = (__half*)(ws + z_y) + (size_t)b * n * 24;
            g.part  = (float*)(ws + z_part) + (size_t)b * NB * F1;
            g.outp  = out + b * F2;
            return g;
        };
        GP g0 = mkg(0), g1 = mkg(1);

        int binBlocks = (E + BIN_EPB - 1) / BIN_EPB;
        int NB4 = (NB + 3) / 4;
        (void)hipMemsetAsync(ws + z_bcnt, 0, 4 * (size_t)MAXB * 4, stream);
        k_binD <<<dim3(binBlocks, 2, 2), BIN_TPB, 0, stream>>>(g0, g1, E);
        k_dprep<<<dim3(NB, 2), 256, 0, stream>>>(g0, g1, n);
        k_agg  <<<dim3(8 * NB4), 256, 0, stream>>>(g0, g1, W1, b1, n, NB);
        k_fin  <<<dim3(1, 2), 1024, 0, stream>>>(g0, g1, W2, b2, invN, NB);
    } else {
        // fallback: round-1 algorithm (atomic scatter), ~4.7 MB
        float* wsf   = (float*)d_ws;
        float* fdeg  = wsf;
        float* fwout = wsf + (size_t)n;
        float* faggx = wsf + 2 * (size_t)n;
        float* fsacc = wsf + 2 * (size_t)n + (size_t)F0 * n;
        float* fdinv = fsacc + F1;
        size_t zero_bytes = ((size_t)23 * n + F1) * sizeof(float);
        for (int b = 0; b < 2; ++b) {
            (void)hipMemsetAsync(wsf, 0, zero_bytes, stream);
            const int* srcp = (const int*)d_in[2 + b];
            const int* dstp = srcp + E;
            const float* x = (const float*)d_in[b];
            o_deg <<<1024, 256, 0, stream>>>(dstp, fdeg, E);
            o_dinv<<<(n + 255) / 256, 256, 0, stream>>>(fdeg, fdinv, n);
            o_edge<<<2048, 256, 0, stream>>>(srcp, dstp, x, fdinv, fwout, faggx, E);
            o_node<<<512, F1, 0, stream>>>(x, faggx, fdinv, fwout, W1, b1, fsacc, n);
            o_final<<<1, F2, 0, stream>>>(fsacc, W2, b2, out + b * F2, invN);
        }
    }
}